// Round 8
// baseline (294.012 us; speedup 1.0000x reference)
//
#include <hip/hip_runtime.h>

// Problem: B=256, N=8192, K=16, fp32.
// out[b,n,k] = min(y[n], 0.5*(y[n-1]+y[n+1])) - param   (interior n)
//            = y[n] - param                              (n==0 or n==N-1)
// where y = x + param. Pure memory-bound 3-point stencil along N.
//
// V8 = V7 (nt input loads — the big win: kernel dropped below the 80us
// fill dispatches in the profile) + ONE structural tweak: tile doubled to
// 128 rows / 512 threads (16384 blocks instead of 32768). Halves per-block
// fixed cost (dispatch, LDS alloc, sync) and halo duplication; the two
// halo loads are issued by two DIFFERENT waves (wave 0 top, last wave
// bottom) so no single wave's load queue is the block critical path.
// Stores stay plain/cached (V5: nt stores regress; with reads bypassing
// the LLC, the 134 MB write stream has the whole 256 MB L3 to land in).

#define B_    256
#define N_    8192
#define K_    16
#define TILE  128          // n-rows per block
#define TPB   512
#define KQ    4            // K/4 float4 columns per row
#define NTILES (N_ / TILE) // 64

static_assert(TILE * KQ == TPB, "one thread per float4 of the tile");

typedef float nfloat4 __attribute__((ext_vector_type(4)));

__device__ __forceinline__ float4 nt_load(const float4* p) {
    nfloat4 v = __builtin_nontemporal_load(reinterpret_cast<const nfloat4*>(p));
    return make_float4(v.x, v.y, v.z, v.w);
}

__global__ __launch_bounds__(TPB)
void convex_kernel(const float4* __restrict__ x4,
                   const float4* __restrict__ p4,
                   float4* __restrict__ o4)
{
    // y-tile with 1-row halo on each side: 130 rows x 4 float4 = 8320 B LDS
    __shared__ float4 ysh[TILE + 2][KQ];

    const int tid = threadIdx.x;
    const int row = tid >> 2;     // 0..127 : n-row within tile
    const int col = tid & 3;      // 0..3   : float4 column within K
    const int blk = blockIdx.x;
    const int t   = blk & (NTILES - 1);  // tile index along N
    const int b   = blk >> 6;            // batch (NTILES == 64)
    const int n0  = t * TILE;

    const long base = ((long)b * N_ + n0) * KQ;   // float4 index of tile origin
    const long idx  = base + (long)row * KQ + col;

    // Main load: each element of x/param read exactly once.
    float4 xv = nt_load(&x4[idx]);
    float4 pv = nt_load(&p4[idx]);
    float4 yv = make_float4(xv.x + pv.x, xv.y + pv.y, xv.z + pv.z, xv.w + pv.w);
    ysh[row + 1][col] = yv;

    // Halo rows, issued by two different waves so neither wave carries both:
    //   wave 0, lanes 0..3    -> row n0-1
    //   last wave, lanes 60..63 -> row n0+TILE
    // Guarded at the array ends (those values are never consumed there:
    // boundary rows take the y-param path).
    if (tid < 4) {
        float4 h = make_float4(0.f, 0.f, 0.f, 0.f);
        if (n0 > 0) {
            float4 hx = nt_load(&x4[base - KQ + col]);
            float4 hp = nt_load(&p4[base - KQ + col]);
            h = make_float4(hx.x + hp.x, hx.y + hp.y, hx.z + hp.z, hx.w + hp.w);
        }
        ysh[0][col] = h;
    } else if (tid >= TPB - 4) {
        float4 h = make_float4(0.f, 0.f, 0.f, 0.f);
        if (n0 + TILE < N_) {
            float4 hx = nt_load(&x4[base + (long)TILE * KQ + col]);
            float4 hp = nt_load(&p4[base + (long)TILE * KQ + col]);
            h = make_float4(hx.x + hp.x, hx.y + hp.y, hx.z + hp.z, hx.w + hp.w);
        }
        ysh[TILE + 1][col] = h;
    }
    __syncthreads();

    const int n = n0 + row;
    float4 r;
    if (n == 0 || n == N_ - 1) {
        // Dy padded to 0 at the ends -> out = y - param
        r = make_float4(yv.x - pv.x, yv.y - pv.y, yv.z - pv.z, yv.w - pv.w);
    } else {
        float4 a = ysh[row][col];      // y[n-1]
        float4 d = ysh[row + 2][col];  // y[n+1]
        float4 m = make_float4(0.5f * (a.x + d.x), 0.5f * (a.y + d.y),
                               0.5f * (a.z + d.z), 0.5f * (a.w + d.w));
        r = make_float4(fminf(yv.x, m.x) - pv.x,
                        fminf(yv.y, m.y) - pv.y,
                        fminf(yv.z, m.z) - pv.z,
                        fminf(yv.w, m.w) - pv.w);
    }
    o4[idx] = r;
}

extern "C" void kernel_launch(void* const* d_in, const int* in_sizes, int n_in,
                              void* d_out, int out_size, void* d_ws, size_t ws_size,
                              hipStream_t stream)
{
    const float4* x = (const float4*)d_in[0];
    const float4* p = (const float4*)d_in[1];
    float4*       o = (float4*)d_out;

    dim3 grid(B_ * NTILES);   // 16384 blocks
    dim3 block(TPB);
    convex_kernel<<<grid, block, 0, stream>>>(x, p, o);
}